// Round 2
// baseline (459.142 us; speedup 1.0000x reference)
//
#include <hip/hip_runtime.h>

#define N_NODES 50000
#define E_EDGES 600000
#define D_IN 128
#define O_OUT 128
#define R_REL 8
#define B_BAS 4
#define NCOL 640  // B*O (basis outputs) + O (self-loop)

// Repack basis_v [B,D,O] + w_loop [D,O] -> Bcat [D, 640] row-major:
//   Bcat[d, b*128+o] = basis_v[b,d,o];  Bcat[d, 512+o] = w_loop[d,o]
__global__ void repack_kernel(const float* __restrict__ basis_v,
                              const float* __restrict__ w_loop,
                              float* __restrict__ Bcat) {
    int i = blockIdx.x * 256 + threadIdx.x;  // over D*NCOL = 81920
    if (i >= D_IN * NCOL) return;
    int d = i / NCOL, j = i % NCOL;
    float v;
    if (j < B_BAS * O_OUT)
        v = basis_v[(j >> 7) * (D_IN * O_OUT) + d * O_OUT + (j & 127)];
    else
        v = w_loop[d * O_OUT + (j - B_BAS * O_OUT)];
    Bcat[i] = v;
}

// Per-(relation,dst) in-degree
__global__ void deg_kernel(const int* __restrict__ rel, const int* __restrict__ dst,
                           float* __restrict__ deg) {
    int e = blockIdx.x * 256 + threadIdx.x;
    if (e >= E_EDGES) return;
    atomicAdd(&deg[rel[e] * N_NODES + dst[e]], 1.0f);
}

// C[N,640] = x[N,128] @ Bcat[128,640]   (fp32 vector GEMM, full K in LDS)
__global__ __launch_bounds__(256) void gemm_kernel(const float* __restrict__ A,
                                                   const float* __restrict__ Bcat,
                                                   float* __restrict__ C) {
    __shared__ float As[64][132];  // +4 pad: float4-aligned, breaks bank aliasing
    __shared__ float Bs[128][68];
    int jn = blockIdx.x * 64;   // 10 col tiles (fastest-varying: B reuse in L2)
    int row0 = blockIdx.y * 64; // 782 row tiles
    int t = threadIdx.x;

    // stage A tile: 64 x 128 floats
    #pragma unroll
    for (int i = 0; i < 8; ++i) {
        int flat = t * 4 + i * 1024;
        int r = flat >> 7, c = flat & 127;
        float4 v = make_float4(0.f, 0.f, 0.f, 0.f);
        if (row0 + r < N_NODES) v = *(const float4*)&A[(size_t)(row0 + r) * D_IN + c];
        *(float4*)&As[r][c] = v;
    }
    // stage B tile: 128 x 64 floats
    #pragma unroll
    for (int i = 0; i < 8; ++i) {
        int flat = t * 4 + i * 1024;
        int r = flat >> 6, c = flat & 63;
        *(float4*)&Bs[r][c] = *(const float4*)&Bcat[(size_t)r * NCOL + jn + c];
    }
    __syncthreads();

    int tx = t & 15, ty = t >> 4;
    float acc[4][4] = {};
    #pragma unroll 4
    for (int k = 0; k < 128; ++k) {
        float a[4], b[4];
        #pragma unroll
        for (int i = 0; i < 4; ++i) a[i] = As[ty * 4 + i][k];
        #pragma unroll
        for (int j = 0; j < 4; ++j) b[j] = Bs[k][tx * 4 + j];
        #pragma unroll
        for (int i = 0; i < 4; ++i)
            #pragma unroll
            for (int j = 0; j < 4; ++j) acc[i][j] += a[i] * b[j];
    }

    #pragma unroll
    for (int i = 0; i < 4; ++i) {
        int n = row0 + ty * 4 + i;
        if (n < N_NODES) {
            float4 v = make_float4(acc[i][0], acc[i][1], acc[i][2], acc[i][3]);
            *(float4*)&C[(size_t)n * NCOL + jn + tx * 4] = v;
        }
    }
}

// Per edge: msg[o] = inv_deg * sum_b coeffs[rel,b] * C[src, b*128+o]; atomic add to out[dst]
__global__ __launch_bounds__(256) void scatter_kernel(const int* __restrict__ src,
                                                      const int* __restrict__ dst,
                                                      const int* __restrict__ rel,
                                                      const float* __restrict__ coeffs,
                                                      const float* __restrict__ C,
                                                      const float* __restrict__ deg,
                                                      float* __restrict__ out) {
    int e = blockIdx.x * 2 + (threadIdx.x >> 7);
    int o = threadIdx.x & 127;
    int s = src[e], d = dst[e], r = rel[e];
    float dg = deg[r * N_NODES + d];
    float inv = 1.0f / fmaxf(dg, 1.0f);
    const float* row = C + (size_t)s * NCOL;
    float c0 = coeffs[r * B_BAS + 0], c1 = coeffs[r * B_BAS + 1];
    float c2 = coeffs[r * B_BAS + 2], c3 = coeffs[r * B_BAS + 3];
    float v = c0 * row[o] + c1 * row[128 + o] + c2 * row[256 + o] + c3 * row[384 + o];
    atomicAdd(&out[(size_t)d * O_OUT + o], v * inv);
}

// out = relu(agg + selfloop_cols + bias)
__global__ void final_kernel(const float* __restrict__ C, const float* __restrict__ bias,
                             float* __restrict__ out) {
    int i = blockIdx.x * 256 + threadIdx.x;  // over N*O
    int n = i >> 7, o = i & 127;
    float v = out[i] + C[(size_t)n * NCOL + B_BAS * O_OUT + o] + bias[o];
    out[i] = fmaxf(v, 0.0f);
}

extern "C" void kernel_launch(void* const* d_in, const int* in_sizes, int n_in,
                              void* d_out, int out_size, void* d_ws, size_t ws_size,
                              hipStream_t stream) {
    (void)in_sizes; (void)n_in; (void)out_size; (void)ws_size;
    const float* x       = (const float*)d_in[0];
    const float* basis_v = (const float*)d_in[1];
    const float* coeffs  = (const float*)d_in[2];
    const float* w_loop  = (const float*)d_in[3];
    const float* bias_p  = (const float*)d_in[4];
    const int*   src     = (const int*)d_in[5];
    const int*   dst     = (const int*)d_in[6];
    const int*   rel     = (const int*)d_in[7];
    float* out = (float*)d_out;

    char* ws = (char*)d_ws;
    float* Bcat = (float*)ws;                                   // 128*640*4   = 327,680 B
    float* C    = (float*)(ws + 327680);                        // 50000*640*4 = 128,000,000 B
    float* deg  = (float*)(ws + 327680 + 128000000);            // 8*50000*4   = 1,600,000 B

    hipMemsetAsync(out, 0, (size_t)N_NODES * O_OUT * sizeof(float), stream);
    hipMemsetAsync(deg, 0, (size_t)R_REL * N_NODES * sizeof(float), stream);

    repack_kernel<<<(D_IN * NCOL + 255) / 256, 256, 0, stream>>>(basis_v, w_loop, Bcat);
    deg_kernel<<<(E_EDGES + 255) / 256, 256, 0, stream>>>(rel, dst, deg);
    gemm_kernel<<<dim3(NCOL / 64, (N_NODES + 63) / 64), 256, 0, stream>>>(x, Bcat, C);
    scatter_kernel<<<E_EDGES / 2, 256, 0, stream>>>(src, dst, rel, coeffs, C, deg, out);
    final_kernel<<<(N_NODES * O_OUT) / 256, 256, 0, stream>>>(C, bias_p, out);
}